// Round 6
// baseline (38.579 us; speedup 1.0000x reference)
//
#include <hip/hip_runtime.h>

// RNN(tanh) fused forward — producer/consumer v3 (TLP for memory duty cycle).
// T=512, B=32768, H=2. 512 blocks x 128 threads -> 2 blocks/CU so one
// block's compute covers the other's barrier vmcnt drain.
// wave0 = consumer: 64 chains, h in registers, LDS-only traffic.
// wave1 = producer: DMA-stages x (triple-buffered ring, 2 chunks ahead) via
// global_load_lds(16B), and runs the output stream (exp2(f.h+b) + NT store)
// one chunk behind from the h ring.

#define T_STEPS 512
#define BATCH   32768
#define CH      16              // timesteps per chunk
#define NCH     (T_STEPS / CH)  // 32 chunks

typedef float v2f __attribute__((ext_vector_type(2)));

__global__ __launch_bounds__(128) void rnn_pc3_kernel(
    const v2f*   __restrict__ x,     // [T][B] float2
    const float* __restrict__ W_ih,  // [2][2]
    const float* __restrict__ W_hh,  // [2][2]
    const float* __restrict__ b_ih,  // [2]
    const float* __restrict__ b_hh,  // [2]
    const float* __restrict__ fc_w,  // [1][2]
    const float* __restrict__ fc_b,  // [1]
    float*       __restrict__ out)   // [T*B] output, then [B][2] h_last
{
    __shared__ v2f xbuf[3][CH][64];   // 24KB: x ring, 2 chunks prefetch
    __shared__ v2f hbuf[2][CH][64];   // 16KB: h ring

    const int tid  = threadIdx.x;
    const int wave = tid >> 6;
    const int lane = tid & 63;
    const size_t bbase = (size_t)blockIdx.x * 64;

    const float L2E = 1.44269504088896340736f;   // log2(e)

    if (wave == 1) {
        // ---------------- producer ----------------
        const float f0 = fc_w[0]*L2E, f1 = fc_w[1]*L2E, fb = fc_b[0]*L2E;
        float* op = out + bbase + lane;

        // one gload_lds covers 2 rows (64 lanes x 16B = 1KB; row = 512B)
        const int rofs = lane >> 5;           // 0 or 1: which row of the pair
        const int cofs = (lane & 31) * 2;     // v2f offset within row

        // prologue: chunks 0,1 -> slots 0,1
        #pragma unroll
        for (int k = 0; k < CH; ++k) {        // 16 row-pairs over 2 chunks
            const int row = 2 * k;            // 0..30 within the 32-step window
            const v2f* src = x + ((size_t)(row + rofs)) * BATCH + bbase + cofs;
            __builtin_amdgcn_global_load_lds(
                (const __attribute__((address_space(1))) void*)src,
                (__attribute__((address_space(3))) void*)(&xbuf[0][0][0] + (size_t)row * 64 + lane * 2),
                16, 0, 0);
        }
        __syncthreads();

        for (int c = 0; c < NCH; ++c) {
            // (a) prefetch chunk c+2 into slot (c+2)%3
            if (c + 2 < NCH) {
                const size_t t0 = (size_t)(c + 2) * CH;
                const int s = (c + 2) % 3;
                #pragma unroll
                for (int k = 0; k < CH / 2; ++k) {
                    const v2f* src = x + (t0 + 2 * k + rofs) * BATCH + bbase + cofs;
                    __builtin_amdgcn_global_load_lds(
                        (const __attribute__((address_space(1))) void*)src,
                        (__attribute__((address_space(3))) void*)(&xbuf[s][2 * k][0] + lane * 2),
                        16, 0, 0);
                }
            }
            // (b) output stream for chunk c-1
            if (c > 0) {
                const int tb = (c - 1) * CH;
                #pragma unroll
                for (int i = 0; i < CH; ++i) {
                    const v2f hv = hbuf[(c - 1) & 1][i][lane];
                    const float z = fmaf(hv.x, f0, fmaf(hv.y, f1, fb));
                    __builtin_nontemporal_store(__builtin_amdgcn_exp2f(z),
                                                &op[(size_t)(tb + i) * BATCH]);
                }
            }
            __syncthreads();
        }
        // epilogue: output stream for final chunk
        {
            const int tb = (NCH - 1) * CH;
            #pragma unroll
            for (int i = 0; i < CH; ++i) {
                const v2f hv = hbuf[(NCH - 1) & 1][i][lane];
                const float z = fmaf(hv.x, f0, fmaf(hv.y, f1, fb));
                __builtin_nontemporal_store(__builtin_amdgcn_exp2f(z),
                                            &op[(size_t)(tb + i) * BATCH]);
            }
        }
    } else {
        // ---------------- consumer ----------------
        const float S = 2.0f * L2E;  // pre-scale: a' = 2*log2e*a feeds exp2
        const float w00 = W_ih[0]*S, w01 = W_ih[1]*S, w10 = W_ih[2]*S, w11 = W_ih[3]*S;
        const float u00 = W_hh[0]*S, u01 = W_hh[1]*S, u10 = W_hh[2]*S, u11 = W_hh[3]*S;
        const float bi0 = (b_ih[0] + b_hh[0])*S, bi1 = (b_ih[1] + b_hh[1])*S;

        float h0 = 0.0f, h1 = 0.0f;

        __syncthreads();   // matches producer prologue barrier

        for (int c = 0; c < NCH; ++c) {
            const int s = c % 3;
            #pragma unroll
            for (int i = 0; i < CH; ++i) {
                const v2f xv = xbuf[s][i][lane];

                float a0 = fmaf(xv.x, w00, fmaf(xv.y, w01, bi0));
                float a1 = fmaf(xv.x, w10, fmaf(xv.y, w11, bi1));
                a0 = fmaf(h1, u01, a0);  a0 = fmaf(h0, u00, a0);
                a1 = fmaf(h0, u10, a1);  a1 = fmaf(h1, u11, a1);

                // tanh(a) = 1 - 2/(exp2(a')+1)
                const float e0 = __builtin_amdgcn_exp2f(a0);
                const float e1 = __builtin_amdgcn_exp2f(a1);
                h0 = fmaf(-2.0f, __builtin_amdgcn_rcpf(e0 + 1.0f), 1.0f);
                h1 = fmaf(-2.0f, __builtin_amdgcn_rcpf(e1 + 1.0f), 1.0f);

                v2f hv; hv.x = h0; hv.y = h1;
                hbuf[c & 1][i][lane] = hv;
            }
            __syncthreads();
        }

        // h_last: [1][B][2] — one 8B store per lane
        v2f hv; hv.x = h0; hv.y = h1;
        __builtin_nontemporal_store(hv, (v2f*)(out + (size_t)T_STEPS * BATCH) + bbase + lane);
    }
}

extern "C" void kernel_launch(void* const* d_in, const int* in_sizes, int n_in,
                              void* d_out, int out_size, void* d_ws, size_t ws_size,
                              hipStream_t stream) {
    const v2f*   x    = (const v2f*)d_in[0];
    const float* W_ih = (const float*)d_in[1];
    const float* W_hh = (const float*)d_in[2];
    const float* b_ih = (const float*)d_in[3];
    const float* b_hh = (const float*)d_in[4];
    const float* fc_w = (const float*)d_in[5];
    const float* fc_b = (const float*)d_in[6];
    float* out = (float*)d_out;

    rnn_pc3_kernel<<<dim3(BATCH / 64), dim3(128), 0, stream>>>(
        x, W_ih, W_hh, b_ih, b_hh, fc_w, fc_b, out);
}